// Round 1
// 105.681 us; speedup vs baseline: 1.0190x; 1.0190x over previous
//
#include <hip/hip_runtime.h>
#include <math.h>

// Problem constants (from reference)
#define LSEQ   129      // PL + 1
#define PLEN   128
#define NHEAD  8
#define DHEAD  32
#define INNER  256      // NHEAD * V_DIM
#define HID    1024     // 4 * INNER

typedef _Float16 h2 __attribute__((ext_vector_type(2)));
typedef _Float16 h4 __attribute__((ext_vector_type(4)));
typedef _Float16 h8 __attribute__((ext_vector_type(8)));   // 16 B = 4 VGPRs
typedef float    f32x4 __attribute__((ext_vector_type(4)));

// -------------------------------------------------------------------------
// Kernel 1: single-query (l=0) attention (algebraically collapsed) PLUS
// weight repack prologue (fp32 -> K-oct fp16, 16 B elements).
//
// Repack layouts (K-major octs, columns contiguous for coalescing):
//   W1o[c8*1024 + j]: halves W1[8c8+i][j], i=0..7   (c8<32)
//   W2o[c8*256  + o]: halves W2[8c8+i][o]           (c8<128)
//   Woo[c8*256  + o]: halves Wo[8c8+i][o]           (c8<32)
// 73728 pack items over 1024x256 threads: blocks 0..287 do one item each.
// NOTE: the K-oct layout is EXACTLY the B-fragment layout of
// v_mfma_f32_16x16x32_f16 (lane l -> oct c8 = k0/8 + (l>>4), col n0+(l&15)),
// so the MFMA mlp_kernel below consumes these buffers with one
// global_load_dwordx4 per fragment. Do not change this layout.
//
// Attention identity (RoPE rotation-invariance + rank-2 K/V):
//   score[h,m] = x0_m*sum_j(c*A0+s*B0) + x1_m*sum_j(c*A1+s*B1),
//   D=(t_m-t_0)*invf_j;  ctx[h,d] = (S0_h*wv0 + S1_h*wv1)/den_h.
// NOTE (r6 post-mortem): do NOT fuse this with the MLP kernel — fusion
// forces 1 block/CU (99 KB LDS) and serializes 4 rows behind shared
// barriers; measured +3.9 us vs this 2-kernel structure.
// -------------------------------------------------------------------------
__global__ __launch_bounds__(256) void attn_kernel(
    const float* __restrict__ x,      // (BN, PL, 2)
    const float* __restrict__ t,      // (BN, L)
    const int*   __restrict__ mask,   // (BN, L)
    const float* __restrict__ emb,    // (2,)
    const float* __restrict__ Wq,     // (2, 256)
    const float* __restrict__ Wk,     // (2, 256)
    const float* __restrict__ Wv,     // (2, 256)
    const float* __restrict__ W1,     // (256, 1024)
    const float* __restrict__ W2,     // (1024, 256)
    const float* __restrict__ Wo,     // (256, 256)
    float*       __restrict__ last,   // (BN, 256)
    h8*          __restrict__ W1o,
    h8*          __restrict__ W2o,
    h8*          __restrict__ Woo)
{
    const int bn  = blockIdx.x;
    const int tid = threadIdx.x;

    // ---- Weight repack prologue (independent of LDS phases) ----
    {
        int g = bn * 256 + tid;
        if (g < 73728) {
            h8 v;
            if (g < 32768) {                 // W1: c8<32, j<1024
                int c8 = g >> 10, j = g & 1023;
                const float* src = W1 + (8 * c8) * HID + j;
#pragma unroll
                for (int i = 0; i < 8; ++i) v[i] = (_Float16)src[i * HID];
                W1o[g] = v;
            } else if (g < 65536) {          // W2: c8<128, o<256
                int l = g - 32768;
                int c8 = l >> 8, o = l & 255;
                const float* src = W2 + (8 * c8) * INNER + o;
#pragma unroll
                for (int i = 0; i < 8; ++i) v[i] = (_Float16)src[i * INNER];
                W2o[l] = v;
            } else {                         // Wo: c8<32, o<256
                int l = g - 65536;
                int c8 = l >> 8, o = l & 255;
                const float* src = Wo + (8 * c8) * INNER + o;
#pragma unroll
                for (int i = 0; i < 8; ++i) v[i] = (_Float16)src[i * INNER];
                Woo[l] = v;
            }
        }
    }

    __shared__ float2 cs_s[16][132];   // [j][m]; 132 pad -> 2-way max
    __shared__ float2 x_s[132];        // x pairs; x_s[0] = emb
    __shared__ float4 ab_s[8][16];     // (A0,B0,A1,B1) per (h,j), scaled
    __shared__ float  sc_s[8][132];    // scores
    __shared__ int    mask_s[132];
    __shared__ float  hstat_s[8][3];   // den, S0, S1 per head

    const float* tb = t + bn * LSEQ;
    const float t0  = tb[0];
    const float e0 = emb[0], e1 = emb[1];

    // ---- Phase A: stage x/mask, build cs table and AB table ----
    if (tid < 130) {
        float2 v;
        if (tid == 0)        v = make_float2(e0, e1);
        else if (tid <= 128) v = ((const float2*)(x + bn * PLEN * 2))[tid - 1];
        else                 v = make_float2(0.f, 0.f);
        x_s[tid] = v;
    }
    if (tid < 129) mask_s[tid] = mask[bn * LSEQ + tid];

    for (int i = tid; i < 129 * 16; i += 256) {
        int m = i >> 4, j = i & 15;
        float invf = exp2f(-(float)j * 0.8304820237218407f); // 10000^(-2j/32)
        float sv, cv;
        __sincosf((tb[m] - t0) * invf, &sv, &cv);
        cs_s[j][m] = make_float2(cv, sv);
    }

    if (tid < 128) {
        int h = tid >> 4, j = tid & 15;
        int ce = h * 32 + 2 * j, co = ce + 1;
        float qe = e0 * Wq[ce] + e1 * Wq[256 + ce];
        float qo = e0 * Wq[co] + e1 * Wq[256 + co];
        float k0e = Wk[ce], k0o = Wk[co];
        float k1e = Wk[256 + ce], k1o = Wk[256 + co];
        const float sc = 0.17677669529663687f;   // 1/sqrt(32)
        ab_s[h][j] = make_float4((qe * k0e + qo * k0o) * sc,
                                 (qo * k0e - qe * k0o) * sc,
                                 (qe * k1e + qo * k1o) * sc,
                                 (qo * k1e - qe * k1o) * sc);
    }
    __syncthreads();

    // ---- Phase B: scores. Half-wave per head; lane handles m = l32+32k ----
    const int lane = tid & 63;
    const int wv   = tid >> 6;
    const int h    = wv * 2 + (lane >> 5);
    const int l32  = lane & 31;

    float4 ab[16];
#pragma unroll
    for (int j = 0; j < 16; ++j) ab[j] = ab_s[h][j];  // broadcast reads

#pragma unroll
    for (int k = 0; k < 5; ++k) {
        int m = l32 + 32 * k;
        if (m < 129) {
            float2 xv = x_s[m];
            float accA = 0.f, accB = 0.f;
#pragma unroll
            for (int j = 0; j < 16; ++j) {
                float2 cs = cs_s[j][m];
                accA = fmaf(cs.x, ab[j].x, accA);
                accA = fmaf(cs.y, ab[j].y, accA);
                accB = fmaf(cs.x, ab[j].z, accB);
                accB = fmaf(cs.y, ab[j].w, accB);
            }
            sc_s[h][m] = accA * xv.x + accB * xv.y;
        }
    }
    __syncthreads();

    // ---- Phase C: per-head softmax + S0/S1 (reduce over 32 lanes) ----
    const int mask0 = mask_s[0];
    float se[5];
    float M = -1e30f;
#pragma unroll
    for (int k = 0; k < 5; ++k) {
        int m = l32 + 32 * k;
        float s;
        if (m < 129) {
            s = sc_s[h][m];
            if (mask0 == 0)          s = 0.f;     // all masked -> uniform
            else if (mask_s[m] == 0) s = -1e9f;   // exp underflows to 0
        } else s = -1e30f;
        se[k] = s;
        M = fmaxf(M, s);
    }
#pragma unroll
    for (int off = 16; off >= 1; off >>= 1) M = fmaxf(M, __shfl_xor(M, off, 64));

    float den = 0.f, S0 = 0.f, S1 = 0.f;
#pragma unroll
    for (int k = 0; k < 5; ++k) {
        int m = l32 + 32 * k;
        if (m < 129) {
            float e = __expf(se[k] - M);
            float2 xv = x_s[m];
            den += e;
            S0 = fmaf(e, xv.x, S0);
            S1 = fmaf(e, xv.y, S1);
        }
    }
#pragma unroll
    for (int off = 16; off >= 1; off >>= 1) {
        den += __shfl_xor(den, off, 64);
        S0  += __shfl_xor(S0,  off, 64);
        S1  += __shfl_xor(S1,  off, 64);
    }
    if (l32 == 0) {
        hstat_s[h][0] = den; hstat_s[h][1] = S0; hstat_s[h][2] = S1;
    }
    __syncthreads();

    // ---- Phase D: ctx via rank-2 V ----
    {
        int hh = tid >> 5;
        float inv = 1.f / hstat_s[hh][0];
        last[bn * 256 + tid] =
            (hstat_s[hh][1] * Wv[tid] + hstat_s[hh][2] * Wv[256 + tid]) * inv;
    }
}

// -------------------------------------------------------------------------
// Kernel 2 (MFMA rewrite): LayerNorm -> FF1(256->1024)+ReLU ->
// FF2(1024->256)+b2+residual -> Wo (256->256).
//
// 16 rows/block, 64 blocks, 1024 threads (16 waves). Each wave owns one
// LN row, 4 FF1 N-tiles (cols 64w..64w+63), 1 FF2 N-tile, 1 Wo N-tile.
// All GEMMs via v_mfma_f32_16x16x32_f16:
//   A-frag: lane l holds A[l&15][k0 + 8*(l>>4) + i]  -> one ds_read_b128
//   B-frag: lane l holds B[k0+8*(l>>4)+i][n0+(l&15)] -> one K-oct (h8) load
//   C/D:    col = lane&15, row = (lane>>4)*4 + reg   (m89/m91-verified)
// vs the previous dot2 version this removes ~4600 broadcast ds_read_b128
// per CU (was ~23 us of LDS return BW) and cuts the aggregate L2 weight
// stream 288 MB -> 72 MB (4x row reuse).
// LDS row strides padded to (stride/4) % 32 == 4 -> worst 2-way bank
// aliasing on fragment reads (free per m136).
// -------------------------------------------------------------------------
__global__ __launch_bounds__(1024) void mlp_kernel(
    const float* __restrict__ last,  // (BN, 256)
    const float* __restrict__ ln_g,  // (256,)
    const float* __restrict__ ln_b,  // (256,)
    const h8*    __restrict__ W1o,   // (32, 1024) K-octs
    const float* __restrict__ b1,    // (1024,)
    const h8*    __restrict__ W2o,   // (128, 256) K-octs
    const float* __restrict__ b2,    // (256,)
    const h8*    __restrict__ Woo,   // (32, 256)  K-octs
    float*       __restrict__ out)   // (BN, 256)
{
    const int tid  = threadIdx.x;     // 0..1023
    const int w    = tid >> 6;        // wave 0..15
    const int lane = tid & 63;
    const int g    = lane >> 4;       // lane group 0..3 (k-slab / row group)
    const int lr   = lane & 15;       // row (A) / col (B,D) within tile
    const int r0   = blockIdx.x * 16;

    // padded so row stride in dwords % 32 == 4  (2-way max on frag reads)
    __shared__ alignas(16) _Float16 h_h[16][264];    //  8.25 KB post-LN
    __shared__ alignas(16) _Float16 y_h[16][1032];   // 33 KB post-ReLU
    __shared__ alignas(16) _Float16 r_h[16][264];    //  8.25 KB residual
    __shared__ alignas(16) float    last_s[16][260]; // 16.25 KB fp32 residual

    // ---- LayerNorm: wave w owns row w (pure shuffle reduce, no LDS) ----
    {
        float4 v = ((const float4*)(last + (r0 + w) * INNER))[lane];
        *(float4*)&last_s[w][lane * 4] = v;
        float s1 = v.x + v.y + v.z + v.w;
        float s2 = v.x * v.x + v.y * v.y + v.z * v.z + v.w * v.w;
#pragma unroll
        for (int off = 32; off >= 1; off >>= 1) {
            s1 += __shfl_xor(s1, off, 64);
            s2 += __shfl_xor(s2, off, 64);
        }
        float mu  = s1 * (1.f / 256.f);
        float var = s2 * (1.f / 256.f) - mu * mu;
        float rs  = rsqrtf(var + 1e-5f);
        float4 gv = ((const float4*)ln_g)[lane];
        float4 bv = ((const float4*)ln_b)[lane];
        h4 hv;
        hv[0] = (_Float16)((v.x - mu) * rs * gv.x + bv.x);
        hv[1] = (_Float16)((v.y - mu) * rs * gv.y + bv.y);
        hv[2] = (_Float16)((v.z - mu) * rs * gv.z + bv.z);
        hv[3] = (_Float16)((v.w - mu) * rs * gv.w + bv.w);
        *(h4*)&h_h[w][lane * 4] = hv;
    }
    __syncthreads();

    // ---- FF1: wave w -> cols 64w..64w+63 (4 N-tiles), K=256 ----
    {
        f32x4 acc0 = {0.f, 0.f, 0.f, 0.f};
        f32x4 acc1 = {0.f, 0.f, 0.f, 0.f};
        f32x4 acc2 = {0.f, 0.f, 0.f, 0.f};
        f32x4 acc3 = {0.f, 0.f, 0.f, 0.f};
        const int cbase = 64 * w + lr;
        const h8* wp = W1o + g * HID + cbase;
#pragma unroll 2
        for (int k8 = 0; k8 < 32; k8 += 4) {       // k0 = 8*k8
            h8 a = *(const h8*)&h_h[lr][(k8 + g) * 8];
            const h8* wk = wp + k8 * HID;
            acc0 = __builtin_amdgcn_mfma_f32_16x16x32_f16(a, wk[0],  acc0, 0, 0, 0);
            acc1 = __builtin_amdgcn_mfma_f32_16x16x32_f16(a, wk[16], acc1, 0, 0, 0);
            acc2 = __builtin_amdgcn_mfma_f32_16x16x32_f16(a, wk[32], acc2, 0, 0, 0);
            acc3 = __builtin_amdgcn_mfma_f32_16x16x32_f16(a, wk[48], acc3, 0, 0, 0);
        }
        const float b10 = b1[cbase];
        const float b11 = b1[cbase + 16];
        const float b12 = b1[cbase + 32];
        const float b13 = b1[cbase + 48];
#pragma unroll
        for (int r = 0; r < 4; ++r) {
            int row = g * 4 + r;
            y_h[row][cbase]      = (_Float16)fmaxf(acc0[r] + b10, 0.f);
            y_h[row][cbase + 16] = (_Float16)fmaxf(acc1[r] + b11, 0.f);
            y_h[row][cbase + 32] = (_Float16)fmaxf(acc2[r] + b12, 0.f);
            y_h[row][cbase + 48] = (_Float16)fmaxf(acc3[r] + b13, 0.f);
        }
    }
    __syncthreads();

    // ---- FF2: wave w -> cols 16w..16w+15 (1 N-tile), K=1024 ----
    const int col = 16 * w + lr;
    {
        f32x4 acc = {0.f, 0.f, 0.f, 0.f};
        const h8* wp = W2o + g * INNER + col;
#pragma unroll 4
        for (int k8 = 0; k8 < 128; k8 += 4) {
            h8 a = *(const h8*)&y_h[lr][(k8 + g) * 8];
            acc = __builtin_amdgcn_mfma_f32_16x16x32_f16(a, wp[k8 * INNER], acc, 0, 0, 0);
        }
        const float bb = b2[col];
#pragma unroll
        for (int r = 0; r < 4; ++r) {
            int row = g * 4 + r;
            r_h[row][col] = (_Float16)(last_s[row][col] + bb + acc[r]);
        }
    }
    __syncthreads();

    // ---- Wo: wave w -> cols 16w..16w+15, K=256; direct global store ----
    {
        f32x4 acc = {0.f, 0.f, 0.f, 0.f};
        const h8* wp = Woo + g * INNER + col;
#pragma unroll
        for (int k8 = 0; k8 < 32; k8 += 4) {
            h8 a = *(const h8*)&r_h[lr][(k8 + g) * 8];
            acc = __builtin_amdgcn_mfma_f32_16x16x32_f16(a, wp[k8 * INNER], acc, 0, 0, 0);
        }
#pragma unroll
        for (int r = 0; r < 4; ++r)
            out[(r0 + g * 4 + r) * INNER + col] = acc[r];
    }
}

// -------------------------------------------------------------------------
extern "C" void kernel_launch(void* const* d_in, const int* in_sizes, int n_in,
                              void* d_out, int out_size, void* d_ws, size_t ws_size,
                              hipStream_t stream) {
    const float* x    = (const float*)d_in[0];
    const float* t    = (const float*)d_in[1];
    const int*   mask = (const int*)  d_in[2];
    const float* emb  = (const float*)d_in[3];
    const float* Wq   = (const float*)d_in[4];
    const float* Wk   = (const float*)d_in[5];
    const float* Wv   = (const float*)d_in[6];
    const float* Wo   = (const float*)d_in[7];
    const float* ln_g = (const float*)d_in[8];
    const float* ln_b = (const float*)d_in[9];
    const float* W1   = (const float*)d_in[10];
    const float* b1   = (const float*)d_in[11];
    const float* W2   = (const float*)d_in[12];
    const float* b2   = (const float*)d_in[13];
    float* out = (float*)d_out;

    const int BN = in_sizes[1] / LSEQ;   // 1024

    char* ws = (char*)d_ws;
    float* last_ws = (float*)ws;             // 1 MB
    h8* W1o = (h8*)(ws + (1u << 20));        // 512 KB (32768 x 16 B)
    h8* W2o = (h8*)(ws + (1u << 20) + (512u << 10));   // 512 KB
    h8* Woo = (h8*)(ws + (2u << 20));        // 128 KB

    attn_kernel<<<BN, 256, 0, stream>>>(x, t, mask, emb, Wq, Wk, Wv,
                                        W1, W2, Wo, last_ws, W1o, W2o, Woo);
    mlp_kernel<<<BN / 16, 1024, 0, stream>>>(last_ws, ln_g, ln_b, W1o, b1,
                                             W2o, b2, Woo, out);
}